// Round 5
// baseline (3269.329 us; speedup 1.0000x reference)
//
#include <hip/hip_runtime.h>

#define HH 512
#define WW 512
#define HWSZ (HH * WW)
#define NP 2      // points per thread. Spill matrix: NP4+layer-fence -> 256 VGPR
                  // (R1); NP2+layer-fence -> 256 (R2, whole-layer hoist);
                  // NP2+jg-fence+min_waves=3 -> 84 VGPR, activation spill (R3);
                  // scalar-SGPR weights -> AGPR shuffle, 3x VALU (R4).
                  // This round: NP2 + jg-fence + DEFAULT bounds (untried cell).
#define BLK 256

// LDS layout (float offsets). All float4-group bases are 16B-aligned.
#define O_W1 0      // 7x16
#define O_B1 112    // 16
#define O_W2 128    // 16x16
#define O_B2 384    // 16
#define O_W3 400    // 16x16
#define O_B3 656    // 16
#define O_W4 672    // 16x16
#define O_B4 928    // 16
#define O_W5 944    // 16x4 (padded from 16x3)
#define O_B5 1008   // 4 (padded from 3)
#define SW_TOT 1012

// Scheduler fence (mask 0). Placed per jg-group: at most 17 ds_read_b128
// (68 floats) of weights can be in flight -> worst-case live set ~155 VGPR.
// R2 proved per-LAYER fences are too coarse (scheduler hoisted 256 floats).
#define JG_FENCE() __builtin_amdgcn_sched_barrier(0)

// ---------------------------------------------------------------------------
// Pre-pass: transpose featuremap (C,H,W) -> (H,W,C): one bilinear corner = one
// aligned float4 load.
// ---------------------------------------------------------------------------
__global__ void fm_transpose(const float* __restrict__ fm, float* __restrict__ fmT) {
    int i = blockIdx.x * blockDim.x + threadIdx.x;
    if (i < HWSZ) {
        float4 v;
        v.x = fm[i];
        v.y = fm[HWSZ + i];
        v.z = fm[2 * HWSZ + i];
        v.w = fm[3 * HWSZ + i];
        reinterpret_cast<float4*>(fmT)[i] = v;
    }
}

// ---------------------------------------------------------------------------
// Fused grid_sample + MLP, NP=2 points/thread, LDS weights.
// Bottleneck model (corrected in R4 post-mortem): at NP=1 the per-CU LDS
// return bus carries 253 ds_read_b128/wave x 4 cyc x 244 waves/CU ~= 103us —
// MORE than the ~56us of true VALU issue (VALUBusy uses the gfx94x 4-cyc
// formula; gfx950 SIMD-32 issues in 2). NP=2 halves LDS-bus occupancy to
// ~52us and gives each weight read 8 dependent FMAs in 2 independent chains.
// Default launch bounds: allocator sizes to the ~155-float live set (R0
// behavior) instead of over-tightening (R3: min_waves=3 -> 84 VGPR -> spill).
// ---------------------------------------------------------------------------
template <bool TR>
__global__ __launch_bounds__(BLK) void mlp_fused(
    const float* __restrict__ x, const float* __restrict__ fm,
    const float* __restrict__ W1, const float* __restrict__ b1,
    const float* __restrict__ W2, const float* __restrict__ b2,
    const float* __restrict__ W3, const float* __restrict__ b3,
    const float* __restrict__ W4, const float* __restrict__ b4,
    const float* __restrict__ W5, const float* __restrict__ b5,
    float* __restrict__ out, int n)
{
    __shared__ __align__(16) float sW[SW_TOT];
    const int tid = threadIdx.x;

    // ---- stage weights into LDS (one pass; 256 threads) ----
    if (tid < 112) sW[O_W1 + tid] = W1[tid];
    if (tid < 16) {
        sW[O_B1 + tid] = b1[tid];
        sW[O_B2 + tid] = b2[tid];
        sW[O_B3 + tid] = b3[tid];
        sW[O_B4 + tid] = b4[tid];
    }
    {   // W2/W3/W4: exactly one element per thread
        sW[O_W2 + tid] = W2[tid];
        sW[O_W3 + tid] = W3[tid];
        sW[O_W4 + tid] = W4[tid];
    }
    if (tid < 64) {  // W5 padded 16x3 -> 16x4
        int r = tid >> 2, c = tid & 3;
        sW[O_W5 + tid] = (c < 3) ? W5[r * 3 + c] : 0.f;
    }
    if (tid < 4) sW[O_B5 + tid] = (tid < 3) ? b5[tid] : 0.f;
    __syncthreads();

    const int base = blockIdx.x * (BLK * NP) + tid;

    // ---- per-point: load coords, bilinear sample (identical arithmetic to
    //      reference), border clamp ----
    float in[NP][7];
    bool ok[NP];

#pragma unroll
    for (int j = 0; j < NP; ++j) {
        int i = base + j * BLK;
        ok[j] = (i < n);
        int ii = ok[j] ? i : 0;  // clamp OOB lanes to a valid point; store is predicated

        float p0 = x[3 * ii], p1 = x[3 * ii + 1], p2 = x[3 * ii + 2];

        float gx = p0 * 2.f - 1.f;
        float gy = p1 * 2.f - 1.f;
        float fx = ((gx + 1.f) * (float)WW - 1.f) * 0.5f;
        float fy = ((gy + 1.f) * (float)HH - 1.f) * 0.5f;
        fx = fminf(fmaxf(fx, 0.f), (float)(WW - 1));
        fy = fminf(fmaxf(fy, 0.f), (float)(HH - 1));
        float x0f = floorf(fx), y0f = floorf(fy);
        float wx = fx - x0f, wy = fy - y0f;
        int ix0 = (int)x0f, iy0 = (int)y0f;
        int ix1 = min(ix0 + 1, WW - 1);
        int iy1 = min(iy0 + 1, HH - 1);
        float w00 = (1.f - wy) * (1.f - wx);
        float w01 = (1.f - wy) * wx;
        float w10 = wy * (1.f - wx);
        float w11 = wy * wx;

        float feat[4];
        if (TR) {
            const float4* fmT = reinterpret_cast<const float4*>(fm);
            float4 v00 = fmT[iy0 * WW + ix0];
            float4 v01 = fmT[iy0 * WW + ix1];
            float4 v10 = fmT[iy1 * WW + ix0];
            float4 v11 = fmT[iy1 * WW + ix1];
            feat[0] = v00.x * w00 + v01.x * w01 + v10.x * w10 + v11.x * w11;
            feat[1] = v00.y * w00 + v01.y * w01 + v10.y * w10 + v11.y * w11;
            feat[2] = v00.z * w00 + v01.z * w01 + v10.z * w10 + v11.z * w11;
            feat[3] = v00.w * w00 + v01.w * w01 + v10.w * w10 + v11.w * w11;
        } else {
#pragma unroll
            for (int ch = 0; ch < 4; ++ch) {
                const float* f = fm + ch * HWSZ;
                feat[ch] = f[iy0 * WW + ix0] * w00 + f[iy0 * WW + ix1] * w01 +
                           f[iy1 * WW + ix0] * w10 + f[iy1 * WW + ix1] * w11;
            }
        }

        in[j][0] = p0; in[j][1] = p1; in[j][2] = p2;
        in[j][3] = feat[0]; in[j][4] = feat[1];
        in[j][5] = feat[2]; in[j][6] = feat[3];
    }

    // ---- MLP from LDS weights, one jg-group at a time (fenced) ----
    const float4* sW1v = reinterpret_cast<const float4*>(sW + O_W1);
    const float4* sB1v = reinterpret_cast<const float4*>(sW + O_B1);
    const float4* sW2v = reinterpret_cast<const float4*>(sW + O_W2);
    const float4* sB2v = reinterpret_cast<const float4*>(sW + O_B2);
    const float4* sW3v = reinterpret_cast<const float4*>(sW + O_W3);
    const float4* sB3v = reinterpret_cast<const float4*>(sW + O_B3);
    const float4* sW4v = reinterpret_cast<const float4*>(sW + O_W4);
    const float4* sB4v = reinterpret_cast<const float4*>(sW + O_B4);
    const float4* sW5v = reinterpret_cast<const float4*>(sW + O_W5);

    float h[NP][16], g[NP][16];

    // layer 1: 7 -> 16, relu
#pragma unroll
    for (int jg = 0; jg < 4; ++jg) {
        JG_FENCE();
        float4 bb = sB1v[jg];
        float4 a[NP];
#pragma unroll
        for (int j = 0; j < NP; ++j) a[j] = bb;
#pragma unroll
        for (int k = 0; k < 7; ++k) {
            float4 w = sW1v[k * 4 + jg];
#pragma unroll
            for (int j = 0; j < NP; ++j) {
                float u = in[j][k];
                a[j].x = fmaf(u, w.x, a[j].x);
                a[j].y = fmaf(u, w.y, a[j].y);
                a[j].z = fmaf(u, w.z, a[j].z);
                a[j].w = fmaf(u, w.w, a[j].w);
            }
        }
#pragma unroll
        for (int j = 0; j < NP; ++j) {
            h[j][jg * 4 + 0] = fmaxf(a[j].x, 0.f);
            h[j][jg * 4 + 1] = fmaxf(a[j].y, 0.f);
            h[j][jg * 4 + 2] = fmaxf(a[j].z, 0.f);
            h[j][jg * 4 + 3] = fmaxf(a[j].w, 0.f);
        }
    }
    JG_FENCE();

#define LAYER16(WV, BV, src, dst)                                      \
    _Pragma("unroll")                                                  \
    for (int jg = 0; jg < 4; ++jg) {                                   \
        JG_FENCE();                                                    \
        float4 bb = (BV)[jg];                                          \
        float4 a[NP];                                                  \
        _Pragma("unroll")                                              \
        for (int j = 0; j < NP; ++j) a[j] = bb;                        \
        _Pragma("unroll")                                              \
        for (int k = 0; k < 16; ++k) {                                 \
            float4 w = (WV)[k * 4 + jg];                               \
            _Pragma("unroll")                                          \
            for (int j = 0; j < NP; ++j) {                             \
                float u = (src)[j][k];                                 \
                a[j].x = fmaf(u, w.x, a[j].x);                         \
                a[j].y = fmaf(u, w.y, a[j].y);                         \
                a[j].z = fmaf(u, w.z, a[j].z);                         \
                a[j].w = fmaf(u, w.w, a[j].w);                         \
            }                                                          \
        }                                                              \
        _Pragma("unroll")                                              \
        for (int j = 0; j < NP; ++j) {                                 \
            (dst)[j][jg * 4 + 0] = fmaxf(a[j].x, 0.f);                 \
            (dst)[j][jg * 4 + 1] = fmaxf(a[j].y, 0.f);                 \
            (dst)[j][jg * 4 + 2] = fmaxf(a[j].z, 0.f);                 \
            (dst)[j][jg * 4 + 3] = fmaxf(a[j].w, 0.f);                 \
        }                                                              \
    }

    LAYER16(sW2v, sB2v, h, g)
    JG_FENCE();
    LAYER16(sW3v, sB3v, g, h)
    JG_FENCE();
    LAYER16(sW4v, sB4v, h, g)
    JG_FENCE();
#undef LAYER16

    // layer 5: 16 -> 3 (padded to 4), no relu. 17-read window, same bound.
    float4 b5f = *reinterpret_cast<const float4*>(sW + O_B5);
    float4 a5[NP];
#pragma unroll
    for (int j = 0; j < NP; ++j) a5[j] = b5f;
#pragma unroll
    for (int k = 0; k < 16; ++k) {
        float4 w = sW5v[k];
#pragma unroll
        for (int j = 0; j < NP; ++j) {
            float u = g[j][k];
            a5[j].x = fmaf(u, w.x, a5[j].x);
            a5[j].y = fmaf(u, w.y, a5[j].y);
            a5[j].z = fmaf(u, w.z, a5[j].z);
        }
    }
    JG_FENCE();

    // ---- store (12B/lane, contiguous across the wave per j) ----
#pragma unroll
    for (int j = 0; j < NP; ++j) {
        int i = base + j * BLK;
        if (ok[j]) {
            out[3 * i]     = a5[j].x;
            out[3 * i + 1] = a5[j].y;
            out[3 * i + 2] = a5[j].z;
        }
    }
}

extern "C" void kernel_launch(void* const* d_in, const int* in_sizes, int n_in,
                              void* d_out, int out_size, void* d_ws, size_t ws_size,
                              hipStream_t stream) {
    const float* x  = (const float*)d_in[0];
    const float* fm = (const float*)d_in[1];
    const float* W1 = (const float*)d_in[2];
    const float* b1 = (const float*)d_in[3];
    const float* W2 = (const float*)d_in[4];
    const float* b2 = (const float*)d_in[5];
    const float* W3 = (const float*)d_in[6];
    const float* b3 = (const float*)d_in[7];
    const float* W4 = (const float*)d_in[8];
    const float* b4 = (const float*)d_in[9];
    const float* W5 = (const float*)d_in[10];
    const float* b5 = (const float*)d_in[11];
    float* out = (float*)d_out;

    const int n = in_sizes[0] / 3;  // 4,000,000 points
    const int grid = (n + BLK * NP - 1) / (BLK * NP);

    const size_t need = (size_t)HWSZ * 4 * sizeof(float);  // 4 MB
    if (ws_size >= need) {
        float* fmT = (float*)d_ws;
        fm_transpose<<<(HWSZ + 255) / 256, 256, 0, stream>>>(fm, fmT);
        mlp_fused<true><<<grid, BLK, 0, stream>>>(x, fmT, W1, b1, W2, b2, W3, b3,
                                                  W4, b4, W5, b5, out, n);
    } else {
        mlp_fused<false><<<grid, BLK, 0, stream>>>(x, fm, W1, b1, W2, b2, W3, b3,
                                                   W4, b4, W5, b5, out, n);
    }
}

// Round 7
// 196.094 us; speedup vs baseline: 16.6723x; 16.6723x over previous
//
#include <hip/hip_runtime.h>

#define HH 512
#define WW 512
#define HWSZ (HH * WW)
#define BLK 256

// ---- f32 LDS layout (float offsets; all float4 bases 16B-aligned) ----
#define O_W1 0      // 7x16
#define O_B1 112    // 16
#define O_B2 128    // 16
#define O_B3 144    // 16
#define O_B4 160    // 16
#define O_W5 176    // 16x4 (padded from 16x3)
#define O_B5 240    // 4 (padded from 3)
#define SWF_TOT 244

// ---- packed-f16 LDS layout (uint offsets) ----
// Each 16x16 layer: [kp=0..7][j=0..15] dwords, dword = (W[2kp][j], W[2kp+1][j])
#define H_W2 0      // 128 uints
#define H_W3 128    // 128 uints
#define H_W4 256    // 128 uints
#define SH_TOT 384

// Scheduler fence between layers — the R0-proven configuration (NP=1 +
// per-layer fences -> 40 VGPR, no spill). R1-R5 proved every NP>=2 variant
// spills regardless of fence granularity/launch bounds; NP stays 1.
#define LAYER_FENCE() __builtin_amdgcn_sched_barrier(0)

typedef _Float16 half2_t __attribute__((ext_vector_type(2)));

#if defined(__has_builtin)
#if __has_builtin(__builtin_amdgcn_fdot2)
#define FDOT2(a, b, c) __builtin_amdgcn_fdot2((a), (b), (c), false)
#endif
#endif
#ifndef FDOT2
// Fallback: identical numerics at reduced throughput (f16 in, f32 accum).
#define FDOT2(a, b, c) \
    fmaf((float)(a).x, (float)(b).x, fmaf((float)(a).y, (float)(b).y, (c)))
#endif

#define BC_H2(u) __builtin_bit_cast(half2_t, (unsigned)(u))

__device__ inline unsigned pack_f16x2(float a, float b) {
    half2_t p;
    p.x = (_Float16)a;  // RNE convert
    p.y = (_Float16)b;
    return __builtin_bit_cast(unsigned, p);
}

// ---------------------------------------------------------------------------
// Pre-pass: transpose featuremap (C,H,W) -> (H,W,C): one bilinear corner = one
// aligned float4 load.
// ---------------------------------------------------------------------------
__global__ void fm_transpose(const float* __restrict__ fm, float* __restrict__ fmT) {
    int i = blockIdx.x * blockDim.x + threadIdx.x;
    if (i < HWSZ) {
        float4 v;
        v.x = fm[i];
        v.y = fm[HWSZ + i];
        v.z = fm[2 * HWSZ + i];
        v.w = fm[3 * HWSZ + i];
        reinterpret_cast<float4*>(fmT)[i] = v;
    }
}

// ---------------------------------------------------------------------------
// Fused grid_sample + MLP, 1 point/thread.
// R0 bottleneck model (corrected R4): LDS return-bus ~103us/CU (253
// ds_read_b128 broadcasts/point) + true VALU ~52us/SIMD, serialized by the
// load->FMA dependency = 168us. This version halves the traffic by BYTES,
// not by point-count: W2/W3/W4 stored as packed f16 pairs, consumed by
// v_dot2_f32_f16 (2 MACs/instr, f32 accumulate). LDS reads 253 -> ~157/point
// (~64us/CU), VALU ~1030 -> ~800 (~40us/SIMD). L1 and L5 stay full f32.
// Register shape is IDENTICAL to the non-spilling R0 structure (NP=1,
// per-layer fences, fewer in-flight weight regs than R0).
// ---------------------------------------------------------------------------
template <bool TR>
__global__ __launch_bounds__(BLK) void mlp_fused(
    const float* __restrict__ x, const float* __restrict__ fm,
    const float* __restrict__ W1, const float* __restrict__ b1,
    const float* __restrict__ W2, const float* __restrict__ b2,
    const float* __restrict__ W3, const float* __restrict__ b3,
    const float* __restrict__ W4, const float* __restrict__ b4,
    const float* __restrict__ W5, const float* __restrict__ b5,
    float* __restrict__ out, int n)
{
    __shared__ __align__(16) float sW[SWF_TOT];
    __shared__ __align__(16) unsigned sH[SH_TOT];
    const int tid = threadIdx.x;

    // ---- stage weights into LDS ----
    if (tid < 112) sW[O_W1 + tid] = W1[tid];
    if (tid < 16) {
        sW[O_B1 + tid] = b1[tid];
        sW[O_B2 + tid] = b2[tid];
        sW[O_B3 + tid] = b3[tid];
        sW[O_B4 + tid] = b4[tid];
    }
    if (tid < 64) {  // W5 padded 16x3 -> 16x4, f32
        int r = tid >> 2, c = tid & 3;
        sW[O_W5 + tid] = (c < 3) ? W5[r * 3 + c] : 0.f;
    }
    if (tid < 4) sW[O_B5 + tid] = (tid < 3) ? b5[tid] : 0.f;
    {   // W2 (tid 0..127) and W3 (tid 128..255): one packed dword per thread
        const float* Wsrc = (tid < 128) ? W2 : W3;
        int u = tid & 127;
        int kp = u >> 4, j = u & 15;
        unsigned d = pack_f16x2(Wsrc[(2 * kp) * 16 + j], Wsrc[(2 * kp + 1) * 16 + j]);
        sH[((tid < 128) ? H_W2 : H_W3) + u] = d;
    }
    if (tid < 128) {  // W4
        int kp = tid >> 4, j = tid & 15;
        sH[H_W4 + tid] = pack_f16x2(W4[(2 * kp) * 16 + j], W4[(2 * kp + 1) * 16 + j]);
    }
    __syncthreads();

    const int i = blockIdx.x * BLK + tid;
    if (i >= n) return;  // after the barrier: safe

    // ---- load point coords ----
    float p0 = x[3 * i], p1 = x[3 * i + 1], p2 = x[3 * i + 2];

    // ---- bilinear sample, border clamp (identical arithmetic to reference) ----
    float gx = p0 * 2.f - 1.f;
    float gy = p1 * 2.f - 1.f;
    float fx = ((gx + 1.f) * (float)WW - 1.f) * 0.5f;
    float fy = ((gy + 1.f) * (float)HH - 1.f) * 0.5f;
    fx = fminf(fmaxf(fx, 0.f), (float)(WW - 1));
    fy = fminf(fmaxf(fy, 0.f), (float)(HH - 1));
    float x0f = floorf(fx), y0f = floorf(fy);
    float wx = fx - x0f, wy = fy - y0f;
    int ix0 = (int)x0f, iy0 = (int)y0f;
    int ix1 = min(ix0 + 1, WW - 1);
    int iy1 = min(iy0 + 1, HH - 1);
    float w00 = (1.f - wy) * (1.f - wx);
    float w01 = (1.f - wy) * wx;
    float w10 = wy * (1.f - wx);
    float w11 = wy * wx;

    float feat[4];
    if (TR) {
        const float4* fmT = reinterpret_cast<const float4*>(fm);
        float4 v00 = fmT[iy0 * WW + ix0];
        float4 v01 = fmT[iy0 * WW + ix1];
        float4 v10 = fmT[iy1 * WW + ix0];
        float4 v11 = fmT[iy1 * WW + ix1];
        feat[0] = v00.x * w00 + v01.x * w01 + v10.x * w10 + v11.x * w11;
        feat[1] = v00.y * w00 + v01.y * w01 + v10.y * w10 + v11.y * w11;
        feat[2] = v00.z * w00 + v01.z * w01 + v10.z * w10 + v11.z * w11;
        feat[3] = v00.w * w00 + v01.w * w01 + v10.w * w10 + v11.w * w11;
    } else {
#pragma unroll
        for (int ch = 0; ch < 4; ++ch) {
            const float* f = fm + ch * HWSZ;
            feat[ch] = f[iy0 * WW + ix0] * w00 + f[iy0 * WW + ix1] * w01 +
                       f[iy1 * WW + ix0] * w10 + f[iy1 * WW + ix1] * w11;
        }
    }

    const float4* sW1v = reinterpret_cast<const float4*>(sW + O_W1);
    const float4* sB1v = reinterpret_cast<const float4*>(sW + O_B1);
    const float4* sB2v = reinterpret_cast<const float4*>(sW + O_B2);
    const float4* sB3v = reinterpret_cast<const float4*>(sW + O_B3);
    const float4* sB4v = reinterpret_cast<const float4*>(sW + O_B4);
    const float4* sW5v = reinterpret_cast<const float4*>(sW + O_W5);
    const uint4*  sH4  = reinterpret_cast<const uint4*>(sH);

    float in[7] = {p0, p1, p2, feat[0], feat[1], feat[2], feat[3]};
    float h[16], g[16];
    half2_t h2[8];

    LAYER_FENCE();
    // ---- layer 1: 7 -> 16, relu (full f32, inputs exact) ----
#pragma unroll
    for (int jg = 0; jg < 4; ++jg) {
        float4 a = sB1v[jg];
#pragma unroll
        for (int k = 0; k < 7; ++k) {
            float4 w = sW1v[k * 4 + jg];
            float u = in[k];
            a.x = fmaf(u, w.x, a.x);
            a.y = fmaf(u, w.y, a.y);
            a.z = fmaf(u, w.z, a.z);
            a.w = fmaf(u, w.w, a.w);
        }
        h[jg * 4 + 0] = fmaxf(a.x, 0.f);
        h[jg * 4 + 1] = fmaxf(a.y, 0.f);
        h[jg * 4 + 2] = fmaxf(a.z, 0.f);
        h[jg * 4 + 3] = fmaxf(a.w, 0.f);
    }
    LAYER_FENCE();

    // ---- f16 hidden layers: dword = (w[2kp][j], w[2kp+1][j]); uint4 = j..j+3.
    //      4 jg x 8 kp x 4 outputs = 32 uint4 reads, 128 dot2 per layer. ----
#define PACK_ACT(srcf, dst2)                                               \
    _Pragma("unroll")                                                      \
    for (int q = 0; q < 8; ++q) {                                          \
        half2_t p;                                                         \
        p.x = (_Float16)(srcf)[2 * q];                                     \
        p.y = (_Float16)(srcf)[2 * q + 1];                                 \
        (dst2)[q] = p;                                                     \
    }

#define LAYER16H(B4, BV, src2, dst)                                        \
    _Pragma("unroll")                                                      \
    for (int jg = 0; jg < 4; ++jg) {                                       \
        float4 a = (BV)[jg];                                               \
        _Pragma("unroll")                                                  \
        for (int kp = 0; kp < 8; ++kp) {                                   \
            uint4 wq = sH4[(B4) + kp * 4 + jg];                            \
            half2_t u2 = (src2)[kp];                                       \
            a.x = FDOT2(u2, BC_H2(wq.x), a.x);                             \
            a.y = FDOT2(u2, BC_H2(wq.y), a.y);                             \
            a.z = FDOT2(u2, BC_H2(wq.z), a.z);                             \
            a.w = FDOT2(u2, BC_H2(wq.w), a.w);                             \
        }                                                                  \
        (dst)[jg * 4 + 0] = fmaxf(a.x, 0.f);                               \
        (dst)[jg * 4 + 1] = fmaxf(a.y, 0.f);                               \
        (dst)[jg * 4 + 2] = fmaxf(a.z, 0.f);                               \
        (dst)[jg * 4 + 3] = fmaxf(a.w, 0.f);                               \
    }

    PACK_ACT(h, h2)
    LAYER16H(H_W2 / 4, sB2v, h2, g)     // layer 2
    LAYER_FENCE();
    PACK_ACT(g, h2)
    LAYER16H(H_W3 / 4, sB3v, h2, h)     // layer 3
    LAYER_FENCE();
    PACK_ACT(h, h2)
    LAYER16H(H_W4 / 4, sB4v, h2, g)     // layer 4 (output g stays f32)
    LAYER_FENCE();
#undef LAYER16H
#undef PACK_ACT

    // ---- layer 5: 16 -> 3 (padded to 4), full f32, no relu ----
    float4 a5 = *reinterpret_cast<const float4*>(sW + O_B5);
#pragma unroll
    for (int k = 0; k < 16; ++k) {
        float4 w = sW5v[k];
        float u = g[k];
        a5.x = fmaf(u, w.x, a5.x);
        a5.y = fmaf(u, w.y, a5.y);
        a5.z = fmaf(u, w.z, a5.z);
    }

    // ---- store (12B/lane, contiguous across the wave) ----
    out[3 * i]     = a5.x;
    out[3 * i + 1] = a5.y;
    out[3 * i + 2] = a5.z;
}

extern "C" void kernel_launch(void* const* d_in, const int* in_sizes, int n_in,
                              void* d_out, int out_size, void* d_ws, size_t ws_size,
                              hipStream_t stream) {
    const float* x  = (const float*)d_in[0];
    const float* fm = (const float*)d_in[1];
    const float* W1 = (const float*)d_in[2];
    const float* b1 = (const float*)d_in[3];
    const float* W2 = (const float*)d_in[4];
    const float* b2 = (const float*)d_in[5];
    const float* W3 = (const float*)d_in[6];
    const float* b3 = (const float*)d_in[7];
    const float* W4 = (const float*)d_in[8];
    const float* b4 = (const float*)d_in[9];
    const float* W5 = (const float*)d_in[10];
    const float* b5 = (const float*)d_in[11];
    float* out = (float*)d_out;

    const int n = in_sizes[0] / 3;  // 4,000,000 points
    const int grid = (n + BLK - 1) / BLK;

    const size_t need = (size_t)HWSZ * 4 * sizeof(float);  // 4 MB
    if (ws_size >= need) {
        float* fmT = (float*)d_ws;
        fm_transpose<<<(HWSZ + 255) / 256, 256, 0, stream>>>(fm, fmT);
        mlp_fused<true><<<grid, BLK, 0, stream>>>(x, fmT, W1, b1, W2, b2, W3, b3,
                                                  W4, b4, W5, b5, out, n);
    } else {
        mlp_fused<false><<<grid, BLK, 0, stream>>>(x, fm, W1, b1, W2, b2, W3, b3,
                                                   W4, b4, W5, b5, out, n);
    }
}

// Round 8
// 194.916 us; speedup vs baseline: 16.7730x; 1.0060x over previous
//
#include <hip/hip_runtime.h>

#define HH 512
#define WW 512
#define HWSZ (HH * WW)
#define BLK 256

// ---- f32 LDS layout (float offsets; all float4 bases 16B-aligned) ----
#define O_W1 0      // 3x16 (coord rows 0-2 of W1, kept f32: inputs stay exact)
#define O_B1 48     // 16
#define O_B2 64     // 16
#define O_B3 80     // 16
#define O_B4 96     // 16
#define O_B5 112    // 4 (padded from 3)
#define SWF_TOT 116

// ---- packed-f16 LDS layout (uint offsets) ----
// 16x16 layers: [kp=0..7][j=0..15] dwords, dword = (W[2kp][j], W[2kp+1][j]).
// W1F: feat rows 3-6 of W1: [kp=0..1][j], dword = (W1[3+2kp][j], W1[4+2kp][j]).
// W5: [kp=0..7][c=0..3], dword = (W5[2kp][c], W5[2kp+1][c]), c=3 padded 0.
#define H_W1F 0     // 32 uints
#define H_W2 32     // 128 uints
#define H_W3 160    // 128 uints
#define H_W4 288    // 128 uints
#define H_W5 416    // 32 uints
#define SH_TOT 448

// Scheduler fence between layers — the R0/R7-proven configuration (NP=1 +
// per-layer fences -> 36-40 VGPR, no spill). R1-R5 proved every NP>=2
// variant spills regardless of fence granularity/launch bounds.
#define LAYER_FENCE() __builtin_amdgcn_sched_barrier(0)

typedef _Float16 half2_t __attribute__((ext_vector_type(2)));

#if defined(__has_builtin)
#if __has_builtin(__builtin_amdgcn_fdot2)
#define FDOT2(a, b, c) __builtin_amdgcn_fdot2((a), (b), (c), false)
#endif
#endif
#ifndef FDOT2
// Fallback: identical numerics at reduced throughput (f16 in, f32 accum).
#define FDOT2(a, b, c) \
    fmaf((float)(a).x, (float)(b).x, fmaf((float)(a).y, (float)(b).y, (c)))
#endif

#define BC_H2(u) __builtin_bit_cast(half2_t, (unsigned)(u))

__device__ inline unsigned pack_f16x2(float a, float b) {
    half2_t p;
    p.x = (_Float16)a;  // RNE convert
    p.y = (_Float16)b;
    return __builtin_bit_cast(unsigned, p);
}

// ---------------------------------------------------------------------------
// Pre-pass: transpose featuremap (C,H,W) -> (H,W,C): one bilinear corner = one
// aligned float4 load.
// ---------------------------------------------------------------------------
__global__ void fm_transpose(const float* __restrict__ fm, float* __restrict__ fmT) {
    int i = blockIdx.x * blockDim.x + threadIdx.x;
    if (i < HWSZ) {
        float4 v;
        v.x = fm[i];
        v.y = fm[HWSZ + i];
        v.z = fm[2 * HWSZ + i];
        v.w = fm[3 * HWSZ + i];
        reinterpret_cast<float4*>(fmT)[i] = v;
    }
}

// ---------------------------------------------------------------------------
// Fused grid_sample + MLP, 1 point/thread.
// R7 confirmed the model: LDS broadcast-read bus (~64us/CU) serialized with
// true VALU (~35us/SIMD) = 108us. This round finishes the byte-halving:
// L1 feat rows (4 of 7) and W5 also go f16+dot2. Reads/point 157 -> 141
// (L1 32->24, L5 17->9). Coordinate rows of W1 stay f32 (exact inputs);
// hidden layers unchanged from the passing R7 kernel.
// ---------------------------------------------------------------------------
template <bool TR>
__global__ __launch_bounds__(BLK) void mlp_fused(
    const float* __restrict__ x, const float* __restrict__ fm,
    const float* __restrict__ W1, const float* __restrict__ b1,
    const float* __restrict__ W2, const float* __restrict__ b2,
    const float* __restrict__ W3, const float* __restrict__ b3,
    const float* __restrict__ W4, const float* __restrict__ b4,
    const float* __restrict__ W5, const float* __restrict__ b5,
    float* __restrict__ out, int n)
{
    __shared__ __align__(16) float sW[SWF_TOT];
    __shared__ __align__(16) unsigned sH[SH_TOT];
    const int tid = threadIdx.x;

    // ---- stage weights into LDS ----
    if (tid < 48) sW[O_W1 + tid] = W1[tid];   // W1 rows 0-2 (coords), f32
    if (tid < 16) {
        sW[O_B1 + tid] = b1[tid];
        sW[O_B2 + tid] = b2[tid];
        sW[O_B3 + tid] = b3[tid];
        sW[O_B4 + tid] = b4[tid];
    }
    if (tid < 4) sW[O_B5 + tid] = (tid < 3) ? b5[tid] : 0.f;
    if (tid < 32) {  // W1 feat rows 3-6, packed f16
        int kp = tid >> 4, j = tid & 15;
        sH[H_W1F + tid] = pack_f16x2(W1[(3 + 2 * kp) * 16 + j],
                                     W1[(4 + 2 * kp) * 16 + j]);
    }
    {   // W2 (tid 0..127) and W3 (tid 128..255): one packed dword per thread
        const float* Wsrc = (tid < 128) ? W2 : W3;
        int u = tid & 127;
        int kp = u >> 4, j = u & 15;
        unsigned d = pack_f16x2(Wsrc[(2 * kp) * 16 + j], Wsrc[(2 * kp + 1) * 16 + j]);
        sH[((tid < 128) ? H_W2 : H_W3) + u] = d;
    }
    if (tid < 128) {  // W4
        int kp = tid >> 4, j = tid & 15;
        sH[H_W4 + tid] = pack_f16x2(W4[(2 * kp) * 16 + j], W4[(2 * kp + 1) * 16 + j]);
    }
    if (tid >= 128 && tid < 160) {  // W5: 16x3 padded to 16x4, packed f16
        int u = tid - 128;
        int kp = u >> 2, c = u & 3;
        float lo = (c < 3) ? W5[(2 * kp) * 3 + c] : 0.f;
        float hi = (c < 3) ? W5[(2 * kp + 1) * 3 + c] : 0.f;
        sH[H_W5 + u] = pack_f16x2(lo, hi);
    }
    __syncthreads();

    const int i = blockIdx.x * BLK + tid;
    if (i >= n) return;  // after the barrier: safe

    // ---- load point coords ----
    float p0 = x[3 * i], p1 = x[3 * i + 1], p2 = x[3 * i + 2];

    // ---- bilinear sample, border clamp (identical arithmetic to reference) ----
    float gx = p0 * 2.f - 1.f;
    float gy = p1 * 2.f - 1.f;
    float fx = ((gx + 1.f) * (float)WW - 1.f) * 0.5f;
    float fy = ((gy + 1.f) * (float)HH - 1.f) * 0.5f;
    fx = fminf(fmaxf(fx, 0.f), (float)(WW - 1));
    fy = fminf(fmaxf(fy, 0.f), (float)(HH - 1));
    float x0f = floorf(fx), y0f = floorf(fy);
    float wx = fx - x0f, wy = fy - y0f;
    int ix0 = (int)x0f, iy0 = (int)y0f;
    int ix1 = min(ix0 + 1, WW - 1);
    int iy1 = min(iy0 + 1, HH - 1);
    float w00 = (1.f - wy) * (1.f - wx);
    float w01 = (1.f - wy) * wx;
    float w10 = wy * (1.f - wx);
    float w11 = wy * wx;

    float feat[4];
    if (TR) {
        const float4* fmT = reinterpret_cast<const float4*>(fm);
        float4 v00 = fmT[iy0 * WW + ix0];
        float4 v01 = fmT[iy0 * WW + ix1];
        float4 v10 = fmT[iy1 * WW + ix0];
        float4 v11 = fmT[iy1 * WW + ix1];
        feat[0] = v00.x * w00 + v01.x * w01 + v10.x * w10 + v11.x * w11;
        feat[1] = v00.y * w00 + v01.y * w01 + v10.y * w10 + v11.y * w11;
        feat[2] = v00.z * w00 + v01.z * w01 + v10.z * w10 + v11.z * w11;
        feat[3] = v00.w * w00 + v01.w * w01 + v10.w * w10 + v11.w * w11;
    } else {
#pragma unroll
        for (int ch = 0; ch < 4; ++ch) {
            const float* f = fm + ch * HWSZ;
            feat[ch] = f[iy0 * WW + ix0] * w00 + f[iy0 * WW + ix1] * w01 +
                       f[iy1 * WW + ix0] * w10 + f[iy1 * WW + ix1] * w11;
        }
    }

    const float4* sW1v = reinterpret_cast<const float4*>(sW + O_W1);  // 12 float4
    const float4* sB1v = reinterpret_cast<const float4*>(sW + O_B1);
    const float4* sB2v = reinterpret_cast<const float4*>(sW + O_B2);
    const float4* sB3v = reinterpret_cast<const float4*>(sW + O_B3);
    const float4* sB4v = reinterpret_cast<const float4*>(sW + O_B4);
    const uint4*  sH4  = reinterpret_cast<const uint4*>(sH);

    float cin[3] = {p0, p1, p2};
    half2_t f2[2];  // packed feat pairs for L1 f16 rows
    {
        half2_t a, b;
        a.x = (_Float16)feat[0]; a.y = (_Float16)feat[1];
        b.x = (_Float16)feat[2]; b.y = (_Float16)feat[3];
        f2[0] = a; f2[1] = b;
    }

    float h[16], g[16];
    half2_t h2[8];

    LAYER_FENCE();
    // ---- layer 1: 7 -> 16, relu. Coord rows f32 FMA, feat rows f16 dot2. ----
#pragma unroll
    for (int jg = 0; jg < 4; ++jg) {
        float4 a = sB1v[jg];
#pragma unroll
        for (int k = 0; k < 3; ++k) {
            float4 w = sW1v[k * 4 + jg];
            float u = cin[k];
            a.x = fmaf(u, w.x, a.x);
            a.y = fmaf(u, w.y, a.y);
            a.z = fmaf(u, w.z, a.z);
            a.w = fmaf(u, w.w, a.w);
        }
#pragma unroll
        for (int kp = 0; kp < 2; ++kp) {
            uint4 wq = sH4[H_W1F / 4 + kp * 4 + jg];
            half2_t u2 = f2[kp];
            a.x = FDOT2(u2, BC_H2(wq.x), a.x);
            a.y = FDOT2(u2, BC_H2(wq.y), a.y);
            a.z = FDOT2(u2, BC_H2(wq.z), a.z);
            a.w = FDOT2(u2, BC_H2(wq.w), a.w);
        }
        h[jg * 4 + 0] = fmaxf(a.x, 0.f);
        h[jg * 4 + 1] = fmaxf(a.y, 0.f);
        h[jg * 4 + 2] = fmaxf(a.z, 0.f);
        h[jg * 4 + 3] = fmaxf(a.w, 0.f);
    }
    LAYER_FENCE();

    // ---- f16 hidden layers (unchanged from R7) ----
#define PACK_ACT(srcf, dst2)                                               \
    _Pragma("unroll")                                                      \
    for (int q = 0; q < 8; ++q) {                                          \
        half2_t p;                                                         \
        p.x = (_Float16)(srcf)[2 * q];                                     \
        p.y = (_Float16)(srcf)[2 * q + 1];                                 \
        (dst2)[q] = p;                                                     \
    }

#define LAYER16H(B4, BV, src2, dst)                                        \
    _Pragma("unroll")                                                      \
    for (int jg = 0; jg < 4; ++jg) {                                       \
        float4 a = (BV)[jg];                                               \
        _Pragma("unroll")                                                  \
        for (int kp = 0; kp < 8; ++kp) {                                   \
            uint4 wq = sH4[(B4) + kp * 4 + jg];                            \
            half2_t u2 = (src2)[kp];                                       \
            a.x = FDOT2(u2, BC_H2(wq.x), a.x);                             \
            a.y = FDOT2(u2, BC_H2(wq.y), a.y);                             \
            a.z = FDOT2(u2, BC_H2(wq.z), a.z);                             \
            a.w = FDOT2(u2, BC_H2(wq.w), a.w);                             \
        }                                                                  \
        (dst)[jg * 4 + 0] = fmaxf(a.x, 0.f);                               \
        (dst)[jg * 4 + 1] = fmaxf(a.y, 0.f);                               \
        (dst)[jg * 4 + 2] = fmaxf(a.z, 0.f);                               \
        (dst)[jg * 4 + 3] = fmaxf(a.w, 0.f);                               \
    }

    PACK_ACT(h, h2)
    LAYER16H(H_W2 / 4, sB2v, h2, g)     // layer 2
    LAYER_FENCE();
    PACK_ACT(g, h2)
    LAYER16H(H_W3 / 4, sB3v, h2, h)     // layer 3
    LAYER_FENCE();
    PACK_ACT(h, h2)
    LAYER16H(H_W4 / 4, sB4v, h2, g)     // layer 4
    LAYER_FENCE();
#undef LAYER16H

    // ---- layer 5: 16 -> 3 (padded to 4), f16 weights, f32 accum, no relu ----
    PACK_ACT(g, h2)
    float4 a5 = *reinterpret_cast<const float4*>(sW + O_B5);
#pragma unroll
    for (int kp = 0; kp < 8; ++kp) {
        uint4 wq = sH4[H_W5 / 4 + kp];
        half2_t u2 = h2[kp];
        a5.x = FDOT2(u2, BC_H2(wq.x), a5.x);
        a5.y = FDOT2(u2, BC_H2(wq.y), a5.y);
        a5.z = FDOT2(u2, BC_H2(wq.z), a5.z);
    }
#undef PACK_ACT

    // ---- store (12B/lane, contiguous across the wave) ----
    out[3 * i]     = a5.x;
    out[3 * i + 1] = a5.y;
    out[3 * i + 2] = a5.z;
}

extern "C" void kernel_launch(void* const* d_in, const int* in_sizes, int n_in,
                              void* d_out, int out_size, void* d_ws, size_t ws_size,
                              hipStream_t stream) {
    const float* x  = (const float*)d_in[0];
    const float* fm = (const float*)d_in[1];
    const float* W1 = (const float*)d_in[2];
    const float* b1 = (const float*)d_in[3];
    const float* W2 = (const float*)d_in[4];
    const float* b2 = (const float*)d_in[5];
    const float* W3 = (const float*)d_in[6];
    const float* b3 = (const float*)d_in[7];
    const float* W4 = (const float*)d_in[8];
    const float* b4 = (const float*)d_in[9];
    const float* W5 = (const float*)d_in[10];
    const float* b5 = (const float*)d_in[11];
    float* out = (float*)d_out;

    const int n = in_sizes[0] / 3;  // 4,000,000 points
    const int grid = (n + BLK - 1) / BLK;

    const size_t need = (size_t)HWSZ * 4 * sizeof(float);  // 4 MB
    if (ws_size >= need) {
        float* fmT = (float*)d_ws;
        fm_transpose<<<(HWSZ + 255) / 256, 256, 0, stream>>>(fm, fmT);
        mlp_fused<true><<<grid, BLK, 0, stream>>>(x, fmT, W1, b1, W2, b2, W3, b3,
                                                  W4, b4, W5, b5, out, n);
    } else {
        mlp_fused<false><<<grid, BLK, 0, stream>>>(x, fm, W1, b1, W2, b2, W3, b3,
                                                   W4, b4, W5, b5, out, n);
    }
}

// Round 11
// 188.030 us; speedup vs baseline: 17.3872x; 1.0366x over previous
//
#include <hip/hip_runtime.h>

#define HH 512
#define WW 512
#define HWSZ (HH * WW)
#define BLK 256

// ---- f32 weight LDS layout (float offsets) ----
// 16-wide rows padded to stride 20: fragment-gather addr (4*kg+e)*20+jj gives
// bank = jj + 16*kg (mod 32) -> 2-way aliasing = free (m136). Bias bases
// multiple of 4 floats (16B-aligned b128 reads).
#define SW1 20
#define O_W1 0       // 7 rows x 20
#define O_B1 140     // 16
#define O_W2 156     // 16 x 20
#define O_B2 476     // 16
#define O_W3 492     // 16 x 20
#define O_B3 812     // 16
#define O_W4 828     // 16 x 20
#define O_B4 1148    // 16
#define O_W5 1164    // 16 rows x stride 4 (3 used)
#define O_B5 1228    // 16 (rows 3-15 zero)
#define SWF_TOT 1244

// clang's AMDGPU builtins use __fp16 ('h') vectors (R9 lesson).
typedef __fp16 f16x2 __attribute__((ext_vector_type(2)));
typedef __fp16 f16x4 __attribute__((ext_vector_type(4)));
typedef float f32x4 __attribute__((ext_vector_type(4)));

// R10 lesson: do NOT gate this on __has_builtin. In HIP's HOST compilation
// pass the AMDGPU builtins are aux-target (callable inside __global__ bodies)
// but __has_builtin reports FALSE -> macro undefined -> 20 host-pass errors.
// Unconditional define compiles in both passes; the device pass already
// accepted these exact operand types in R10.
#define MFMA16(a, b, c) __builtin_amdgcn_mfma_f32_16x16x16f16((a), (b), (c), 0, 0, 0)

// RNE f32->f16 pair pack (same rounding as the R7/R8 kernels that passed).
__device__ inline unsigned pk2u(float a, float b) {
    f16x2 p;
    p[0] = (__fp16)a;
    p[1] = (__fp16)b;
    return __builtin_bit_cast(unsigned, p);
}

// relu + f32x4 -> f16x4 (next layer's B fragment; element e = k-slot e)
__device__ inline f16x4 relu_pack(f32x4 d) {
    f16x4 r;
    r[0] = (__fp16)fmaxf(d[0], 0.f);
    r[1] = (__fp16)fmaxf(d[1], 0.f);
    r[2] = (__fp16)fmaxf(d[2], 0.f);
    r[3] = (__fp16)fmaxf(d[3], 0.f);
    return r;
}

// ---------------------------------------------------------------------------
// Pre-pass: transpose featuremap (C,H,W) -> (H,W,C): one bilinear corner = one
// aligned float4 load.
// ---------------------------------------------------------------------------
__global__ void fm_transpose(const float* __restrict__ fm, float* __restrict__ fmT) {
    int i = blockIdx.x * blockDim.x + threadIdx.x;
    if (i < HWSZ) {
        float4 v;
        v.x = fm[i];
        v.y = fm[HWSZ + i];
        v.z = fm[2 * HWSZ + i];
        v.w = fm[3 * HWSZ + i];
        reinterpret_cast<float4*>(fmT)[i] = v;
    }
}

// ---------------------------------------------------------------------------
// Fused grid_sample + MLP via per-wave MFMA (H = W^T * X, 16 points/column).
// v_mfma_f32_16x16x16_f16 fragment layout (canonical; C/D family verified on
// gfx950 via the 16x16x32 sibling, m89): A row=l%16, k=4*(l/16)+e;
// B col=l%16, k=4*(l/16)+e; D col=l%16, row=4*(l/16)+e. Since D layout ==
// B layout (col=point, row/k=feature), layers chain with relu+f16-pack ONLY —
// no cross-lane movement. Weights: 5 A-frags (2 VGPR) + 5 bias C-frags
// (4 VGPR) persistent; the per-point LDS weight broadcasts (141/point in R8,
// the dominant ~64us/CU pipe) become ~25 per-lane reads PER WAVE.
// One LDS transpose stages each wave's 64 sampled points into B layout.
// ---------------------------------------------------------------------------
template <bool TR>
__global__ __launch_bounds__(BLK) void mlp_fused(
    const float* __restrict__ x, const float* __restrict__ fm,
    const float* __restrict__ W1, const float* __restrict__ b1,
    const float* __restrict__ W2, const float* __restrict__ b2,
    const float* __restrict__ W3, const float* __restrict__ b3,
    const float* __restrict__ W4, const float* __restrict__ b4,
    const float* __restrict__ W5, const float* __restrict__ b5,
    float* __restrict__ out, int n)
{
    __shared__ __align__(16) float sW[SWF_TOT];
    __shared__ __align__(16) unsigned sX[BLK * 4];  // 4 packed dwords/point (f16 dims 0-7)
    const int tid = threadIdx.x;

    // ---- stage raw f32 weights into LDS (padded strides) ----
    if (tid < 112) { int r = tid >> 4, c = tid & 15; sW[O_W1 + r * SW1 + c] = W1[tid]; }
    if (tid < 16) {
        sW[O_B1 + tid] = b1[tid];
        sW[O_B2 + tid] = b2[tid];
        sW[O_B3 + tid] = b3[tid];
        sW[O_B4 + tid] = b4[tid];
        sW[O_B5 + tid] = (tid < 3) ? b5[tid] : 0.f;  // rows 3-15 zero (padded M)
    }
    {   // W2/W3/W4: one element per thread
        int r = tid >> 4, c = tid & 15;
        sW[O_W2 + r * SW1 + c] = W2[tid];
        sW[O_W3 + r * SW1 + c] = W3[tid];
        sW[O_W4 + r * SW1 + c] = W4[tid];
    }
    if (tid < 48) { int r = tid / 3, c = tid % 3; sW[O_W5 + r * 4 + c] = W5[tid]; }

    // ---- sampling: 1 point/thread (f32, identical arithmetic to reference) ----
    const int i = blockIdx.x * BLK + tid;
    const int ii = (i < n) ? i : (n - 1);  // clamp; store is predicated

    float p0 = x[3 * ii], p1 = x[3 * ii + 1], p2 = x[3 * ii + 2];

    float gx = p0 * 2.f - 1.f;
    float gy = p1 * 2.f - 1.f;
    float fx = ((gx + 1.f) * (float)WW - 1.f) * 0.5f;
    float fy = ((gy + 1.f) * (float)HH - 1.f) * 0.5f;
    fx = fminf(fmaxf(fx, 0.f), (float)(WW - 1));
    fy = fminf(fmaxf(fy, 0.f), (float)(HH - 1));
    float x0f = floorf(fx), y0f = floorf(fy);
    float wx = fx - x0f, wy = fy - y0f;
    int ix0 = (int)x0f, iy0 = (int)y0f;
    int ix1 = min(ix0 + 1, WW - 1);
    int iy1 = min(iy0 + 1, HH - 1);
    float w00 = (1.f - wy) * (1.f - wx);
    float w01 = (1.f - wy) * wx;
    float w10 = wy * (1.f - wx);
    float w11 = wy * wx;

    float feat[4];
    if (TR) {
        const float4* fmT = reinterpret_cast<const float4*>(fm);
        float4 v00 = fmT[iy0 * WW + ix0];
        float4 v01 = fmT[iy0 * WW + ix1];
        float4 v10 = fmT[iy1 * WW + ix0];
        float4 v11 = fmT[iy1 * WW + ix1];
        feat[0] = v00.x * w00 + v01.x * w01 + v10.x * w10 + v11.x * w11;
        feat[1] = v00.y * w00 + v01.y * w01 + v10.y * w10 + v11.y * w11;
        feat[2] = v00.z * w00 + v01.z * w01 + v10.z * w10 + v11.z * w11;
        feat[3] = v00.w * w00 + v01.w * w01 + v10.w * w10 + v11.w * w11;
    } else {
#pragma unroll
        for (int ch = 0; ch < 4; ++ch) {
            const float* f = fm + ch * HWSZ;
            feat[ch] = f[iy0 * WW + ix0] * w00 + f[iy0 * WW + ix1] * w01 +
                       f[iy1 * WW + ix0] * w10 + f[iy1 * WW + ix1] * w11;
        }
    }

    // ---- pack this point's 7 inputs (+pad) as 4 f16-pair dwords; stage ----
    {
        uint4 rec;
        rec.x = pk2u(p0, p1);
        rec.y = pk2u(p2, feat[0]);
        rec.z = pk2u(feat[1], feat[2]);
        rec.w = pk2u(feat[3], 0.f);
        reinterpret_cast<uint4*>(sX)[tid] = rec;  // 16B/lane contiguous
    }
    __syncthreads();

    // ---- per-lane fragment coordinates ----
    const int lane = tid & 63;
    const int wv = tid >> 6;       // wave within block (4 waves, 64 pts each)
    const int jj = lane & 15;      // A: output row m / B,D: point column
    const int kg = lane >> 4;      // k-slot group: k = 4*kg + e

    // ---- gather persistent weight A-fragments + bias C-fragments ----
    f16x4 A1, A2, A3, A4, A5;
#pragma unroll
    for (int e = 0; e < 4; ++e) {
        int k = 4 * kg + e;
        A1[e] = (__fp16)((k < 7) ? sW[O_W1 + k * SW1 + jj] : 0.f);
        A2[e] = (__fp16)sW[O_W2 + k * SW1 + jj];
        A3[e] = (__fp16)sW[O_W3 + k * SW1 + jj];
        A4[e] = (__fp16)sW[O_W4 + k * SW1 + jj];
        A5[e] = (__fp16)((jj < 3) ? sW[O_W5 + k * 4 + jj] : 0.f);
    }
    f32x4 C1 = *reinterpret_cast<const f32x4*>(sW + O_B1 + 4 * kg);
    f32x4 C2 = *reinterpret_cast<const f32x4*>(sW + O_B2 + 4 * kg);
    f32x4 C3 = *reinterpret_cast<const f32x4*>(sW + O_B3 + 4 * kg);
    f32x4 C4 = *reinterpret_cast<const f32x4*>(sW + O_B4 + 4 * kg);
    f32x4 C5 = *reinterpret_cast<const f32x4*>(sW + O_B5 + 4 * kg);

    // ---- load B fragments for the wave's 4 point-groups (L1: k=0..15,
    //      dims 8-15 zero => only kg<2 lanes read) ----
    f16x4 B0, B1f, B2f, B3f;
    {
        const int pb = wv * 64;  // block-local point base for this wave
#define LOADB(Bv, g)                                                         \
        {                                                                    \
            uint2 raw = make_uint2(0u, 0u);                                  \
            if (kg < 2)                                                      \
                raw = *reinterpret_cast<const uint2*>(                       \
                    sX + (pb + (g) * 16 + jj) * 4 + kg * 2);                 \
            (Bv) = __builtin_bit_cast(f16x4, raw);                           \
        }
        LOADB(B0, 0) LOADB(B1f, 1) LOADB(B2f, 2) LOADB(B3f, 3)
#undef LOADB
    }

    // ---- 5-layer MLP: 4 independent MFMA chains (one per 16-point group) ----
    f32x4 D0, D1, D2, D3;
    // layer 1 (K padded 7->16; A zero for k>=7)
    D0 = MFMA16(A1, B0, C1);  D1 = MFMA16(A1, B1f, C1);
    D2 = MFMA16(A1, B2f, C1); D3 = MFMA16(A1, B3f, C1);
    B0 = relu_pack(D0); B1f = relu_pack(D1); B2f = relu_pack(D2); B3f = relu_pack(D3);
    // layer 2
    D0 = MFMA16(A2, B0, C2);  D1 = MFMA16(A2, B1f, C2);
    D2 = MFMA16(A2, B2f, C2); D3 = MFMA16(A2, B3f, C2);
    B0 = relu_pack(D0); B1f = relu_pack(D1); B2f = relu_pack(D2); B3f = relu_pack(D3);
    // layer 3
    D0 = MFMA16(A3, B0, C3);  D1 = MFMA16(A3, B1f, C3);
    D2 = MFMA16(A3, B2f, C3); D3 = MFMA16(A3, B3f, C3);
    B0 = relu_pack(D0); B1f = relu_pack(D1); B2f = relu_pack(D2); B3f = relu_pack(D3);
    // layer 4
    D0 = MFMA16(A4, B0, C4);  D1 = MFMA16(A4, B1f, C4);
    D2 = MFMA16(A4, B2f, C4); D3 = MFMA16(A4, B3f, C4);
    B0 = relu_pack(D0); B1f = relu_pack(D1); B2f = relu_pack(D2); B3f = relu_pack(D3);
    // layer 5 (M padded 3->16, no relu)
    D0 = MFMA16(A5, B0, C5);  D1 = MFMA16(A5, B1f, C5);
    D2 = MFMA16(A5, B2f, C5); D3 = MFMA16(A5, B3f, C5);

    // ---- store: D col=point (jj), row=output dim (4*kg+e) => lanes kg==0
    //      hold dims 0-2 of their group's point in regs 0-2 ----
    if (kg == 0) {
        const int gbase = blockIdx.x * BLK + wv * 64 + jj;
#define STOREG(Dv, g)                                                        \
        {                                                                    \
            int gp = gbase + (g) * 16;                                       \
            if (gp < n) {                                                    \
                out[3 * gp]     = (Dv)[0];                                   \
                out[3 * gp + 1] = (Dv)[1];                                   \
                out[3 * gp + 2] = (Dv)[2];                                   \
            }                                                                \
        }
        STOREG(D0, 0) STOREG(D1, 1) STOREG(D2, 2) STOREG(D3, 3)
#undef STOREG
    }
}

extern "C" void kernel_launch(void* const* d_in, const int* in_sizes, int n_in,
                              void* d_out, int out_size, void* d_ws, size_t ws_size,
                              hipStream_t stream) {
    const float* x  = (const float*)d_in[0];
    const float* fm = (const float*)d_in[1];
    const float* W1 = (const float*)d_in[2];
    const float* b1 = (const float*)d_in[3];
    const float* W2 = (const float*)d_in[4];
    const float* b2 = (const float*)d_in[5];
    const float* W3 = (const float*)d_in[6];
    const float* b3 = (const float*)d_in[7];
    const float* W4 = (const float*)d_in[8];
    const float* b4 = (const float*)d_in[9];
    const float* W5 = (const float*)d_in[10];
    const float* b5 = (const float*)d_in[11];
    float* out = (float*)d_out;

    const int n = in_sizes[0] / 3;  // 4,000,000 points
    const int grid = (n + BLK - 1) / BLK;

    const size_t need = (size_t)HWSZ * 4 * sizeof(float);  // 4 MB
    if (ws_size >= need) {
        float* fmT = (float*)d_ws;
        fm_transpose<<<(HWSZ + 255) / 256, 256, 0, stream>>>(fm, fmT);
        mlp_fused<true><<<grid, BLK, 0, stream>>>(x, fmT, W1, b1, W2, b2, W3, b3,
                                                  W4, b4, W5, b5, out, n);
    } else {
        mlp_fused<false><<<grid, BLK, 0, stream>>>(x, fm, W1, b1, W2, b2, W3, b3,
                                                   W4, b4, W5, b5, out, n);
    }
}

// Round 12
// 164.453 us; speedup vs baseline: 19.8800x; 1.1434x over previous
//
#include <hip/hip_runtime.h>

#define HH 512
#define WW 512
#define HWSZ (HH * WW)
#define BLK 256

// ---- f32 weight LDS layout (float offsets) ----
// 16-wide rows padded to stride 20: fragment-gather addr (4*kg+e)*20+jj gives
// bank = jj + 16*kg (mod 32) -> 2-way aliasing = free (m136). Bias bases
// multiple of 4 floats (16B-aligned b128 reads).
#define SW1 20
#define O_W1 0       // 7 rows x 20
#define O_B1 140     // 16
#define O_W2 156     // 16 x 20
#define O_B2 476     // 16
#define O_W3 492     // 16 x 20
#define O_B3 812     // 16
#define O_W4 828     // 16 x 20
#define O_B4 1148    // 16
#define O_W5 1164    // 16 rows x stride 4 (3 used)
#define O_B5 1228    // 16 (rows 3-15 zero)
#define SWF_TOT 1244

// clang's AMDGPU builtins use __fp16 ('h') vectors (R9 lesson).
typedef __fp16 f16x2 __attribute__((ext_vector_type(2)));
typedef __fp16 f16x4 __attribute__((ext_vector_type(4)));
typedef float f32x4 __attribute__((ext_vector_type(4)));

// R10 lesson: no __has_builtin gating (host pass reports false for aux-target
// builtins); unconditional define compiles in both passes.
#define MFMA16(a, b, c) __builtin_amdgcn_mfma_f32_16x16x16f16((a), (b), (c), 0, 0, 0)

// RNE f32->f16 pair pack.
__device__ inline unsigned pk2u(float a, float b) {
    f16x2 p;
    p[0] = (__fp16)a;
    p[1] = (__fp16)b;
    return __builtin_bit_cast(unsigned, p);
}

// relu + f32x4 -> f16x4 (next layer's B fragment; element e = k-slot e)
__device__ inline f16x4 relu_pack(f32x4 d) {
    f16x4 r;
    r[0] = (__fp16)fmaxf(d[0], 0.f);
    r[1] = (__fp16)fmaxf(d[1], 0.f);
    r[2] = (__fp16)fmaxf(d[2], 0.f);
    r[3] = (__fp16)fmaxf(d[3], 0.f);
    return r;
}

// ---------------------------------------------------------------------------
// Pre-pass: transpose featuremap (C,H,W) f32 -> (H,W,C) f16x4 (8B/pixel).
// R11 diagnosis: the 4 random 16B corner gathers into the 4MB f32 table moved
// a full 64B L2 line each -> ~1.0 GB L2 traffic/dispatch, the binding floor
// (~50-60us at realistic random-access L2 BW). 8B pixels put both x-adjacent
// corners of a row in one line (~135B/pt vs 256B/pt) and shrink the table to
// 2MB (fits per-XCD L2 2x over). fm values ~0.1*N(0,1): f16 quantization
// pre-interp adds <=6e-5 to feat — same channel we already quantize post-
// interp via pk2u with zero absmax movement (R7/R8/R11).
// ---------------------------------------------------------------------------
__global__ void fm_transpose_h(const float* __restrict__ fm, f16x4* __restrict__ fmT) {
    int i = blockIdx.x * blockDim.x + threadIdx.x;
    if (i < HWSZ) {
        f16x4 v;
        v[0] = (__fp16)fm[i];
        v[1] = (__fp16)fm[HWSZ + i];
        v[2] = (__fp16)fm[2 * HWSZ + i];
        v[3] = (__fp16)fm[3 * HWSZ + i];
        fmT[i] = v;
    }
}

// ---------------------------------------------------------------------------
// Fused grid_sample + MLP via per-wave MFMA (H = W^T * X, 16 points/column).
// Verified passing in R11 (absmax unchanged, MfmaUtil 9%, VGPR 36).
// A row=l%16, k=4*(l/16)+e; B col=l%16, k same; D col=l%16, row=4*(l/16)+e.
// D layout == B layout -> layers chain in-register with relu+f16-pack only.
// ---------------------------------------------------------------------------
template <bool TR>
__global__ __launch_bounds__(BLK) void mlp_fused(
    const float* __restrict__ x, const void* __restrict__ fmv,
    const float* __restrict__ W1, const float* __restrict__ b1,
    const float* __restrict__ W2, const float* __restrict__ b2,
    const float* __restrict__ W3, const float* __restrict__ b3,
    const float* __restrict__ W4, const float* __restrict__ b4,
    const float* __restrict__ W5, const float* __restrict__ b5,
    float* __restrict__ out, int n)
{
    __shared__ __align__(16) float sW[SWF_TOT];
    __shared__ __align__(16) unsigned sX[BLK * 4];  // 4 packed dwords/point (f16 dims 0-7)
    const int tid = threadIdx.x;

    // ---- stage raw f32 weights into LDS (padded strides) ----
    if (tid < 112) { int r = tid >> 4, c = tid & 15; sW[O_W1 + r * SW1 + c] = W1[tid]; }
    if (tid < 16) {
        sW[O_B1 + tid] = b1[tid];
        sW[O_B2 + tid] = b2[tid];
        sW[O_B3 + tid] = b3[tid];
        sW[O_B4 + tid] = b4[tid];
        sW[O_B5 + tid] = (tid < 3) ? b5[tid] : 0.f;  // rows 3-15 zero (padded M)
    }
    {   // W2/W3/W4: one element per thread
        int r = tid >> 4, c = tid & 15;
        sW[O_W2 + r * SW1 + c] = W2[tid];
        sW[O_W3 + r * SW1 + c] = W3[tid];
        sW[O_W4 + r * SW1 + c] = W4[tid];
    }
    if (tid < 48) { int r = tid / 3, c = tid % 3; sW[O_W5 + r * 4 + c] = W5[tid]; }

    // ---- sampling: 1 point/thread (f32 weights/coeffs, identical arithmetic) ----
    const int i = blockIdx.x * BLK + tid;
    const int ii = (i < n) ? i : (n - 1);  // clamp; store is predicated

    float p0 = x[3 * ii], p1 = x[3 * ii + 1], p2 = x[3 * ii + 2];

    float gx = p0 * 2.f - 1.f;
    float gy = p1 * 2.f - 1.f;
    float fx = ((gx + 1.f) * (float)WW - 1.f) * 0.5f;
    float fy = ((gy + 1.f) * (float)HH - 1.f) * 0.5f;
    fx = fminf(fmaxf(fx, 0.f), (float)(WW - 1));
    fy = fminf(fmaxf(fy, 0.f), (float)(HH - 1));
    float x0f = floorf(fx), y0f = floorf(fy);
    float wx = fx - x0f, wy = fy - y0f;
    int ix0 = (int)x0f, iy0 = (int)y0f;
    int ix1 = min(ix0 + 1, WW - 1);
    int iy1 = min(iy0 + 1, HH - 1);
    float w00 = (1.f - wy) * (1.f - wx);
    float w01 = (1.f - wy) * wx;
    float w10 = wy * (1.f - wx);
    float w11 = wy * wx;

    float feat[4];
    if (TR) {
        const f16x4* fmH = reinterpret_cast<const f16x4*>(fmv);  // 8B/pixel
        f16x4 h00 = fmH[iy0 * WW + ix0];
        f16x4 h01 = fmH[iy0 * WW + ix1];
        f16x4 h10 = fmH[iy1 * WW + ix0];
        f16x4 h11 = fmH[iy1 * WW + ix1];
#pragma unroll
        for (int ch = 0; ch < 4; ++ch) {
            feat[ch] = (float)h00[ch] * w00 + (float)h01[ch] * w01 +
                       (float)h10[ch] * w10 + (float)h11[ch] * w11;
        }
    } else {
        const float* fmf = reinterpret_cast<const float*>(fmv);
#pragma unroll
        for (int ch = 0; ch < 4; ++ch) {
            const float* f = fmf + ch * HWSZ;
            feat[ch] = f[iy0 * WW + ix0] * w00 + f[iy0 * WW + ix1] * w01 +
                       f[iy1 * WW + ix0] * w10 + f[iy1 * WW + ix1] * w11;
        }
    }

    // ---- pack this point's 7 inputs (+pad) as 4 f16-pair dwords; stage ----
    {
        uint4 rec;
        rec.x = pk2u(p0, p1);
        rec.y = pk2u(p2, feat[0]);
        rec.z = pk2u(feat[1], feat[2]);
        rec.w = pk2u(feat[3], 0.f);
        reinterpret_cast<uint4*>(sX)[tid] = rec;  // 16B/lane contiguous
    }
    __syncthreads();

    // ---- per-lane fragment coordinates ----
    const int lane = tid & 63;
    const int wv = tid >> 6;       // wave within block (4 waves, 64 pts each)
    const int jj = lane & 15;      // A: output row m / B,D: point column
    const int kg = lane >> 4;      // k-slot group: k = 4*kg + e

    // ---- gather persistent weight A-fragments + bias C-fragments ----
    f16x4 A1, A2, A3, A4, A5;
#pragma unroll
    for (int e = 0; e < 4; ++e) {
        int k = 4 * kg + e;
        A1[e] = (__fp16)((k < 7) ? sW[O_W1 + k * SW1 + jj] : 0.f);
        A2[e] = (__fp16)sW[O_W2 + k * SW1 + jj];
        A3[e] = (__fp16)sW[O_W3 + k * SW1 + jj];
        A4[e] = (__fp16)sW[O_W4 + k * SW1 + jj];
        A5[e] = (__fp16)((jj < 3) ? sW[O_W5 + k * 4 + jj] : 0.f);
    }
    f32x4 C1 = *reinterpret_cast<const f32x4*>(sW + O_B1 + 4 * kg);
    f32x4 C2 = *reinterpret_cast<const f32x4*>(sW + O_B2 + 4 * kg);
    f32x4 C3 = *reinterpret_cast<const f32x4*>(sW + O_B3 + 4 * kg);
    f32x4 C4 = *reinterpret_cast<const f32x4*>(sW + O_B4 + 4 * kg);
    f32x4 C5 = *reinterpret_cast<const f32x4*>(sW + O_B5 + 4 * kg);

    // ---- load B fragments for the wave's 4 point-groups (L1: k=0..15,
    //      dims 8-15 zero => only kg<2 lanes read) ----
    f16x4 B0, B1f, B2f, B3f;
    {
        const int pb = wv * 64;  // block-local point base for this wave
#define LOADB(Bv, g)                                                         \
        {                                                                    \
            uint2 raw = make_uint2(0u, 0u);                                  \
            if (kg < 2)                                                      \
                raw = *reinterpret_cast<const uint2*>(                       \
                    sX + (pb + (g) * 16 + jj) * 4 + kg * 2);                 \
            (Bv) = __builtin_bit_cast(f16x4, raw);                           \
        }
        LOADB(B0, 0) LOADB(B1f, 1) LOADB(B2f, 2) LOADB(B3f, 3)
#undef LOADB
    }

    // ---- 5-layer MLP: 4 independent MFMA chains (one per 16-point group) ----
    f32x4 D0, D1, D2, D3;
    // layer 1 (K padded 7->16; A zero for k>=7)
    D0 = MFMA16(A1, B0, C1);  D1 = MFMA16(A1, B1f, C1);
    D2 = MFMA16(A1, B2f, C1); D3 = MFMA16(A1, B3f, C1);
    B0 = relu_pack(D0); B1f = relu_pack(D1); B2f = relu_pack(D2); B3f = relu_pack(D3);
    // layer 2
    D0 = MFMA16(A2, B0, C2);  D1 = MFMA16(A2, B1f, C2);
    D2 = MFMA16(A2, B2f, C2); D3 = MFMA16(A2, B3f, C2);
    B0 = relu_pack(D0); B1f = relu_pack(D1); B2f = relu_pack(D2); B3f = relu_pack(D3);
    // layer 3
    D0 = MFMA16(A3, B0, C3);  D1 = MFMA16(A3, B1f, C3);
    D2 = MFMA16(A3, B2f, C3); D3 = MFMA16(A3, B3f, C3);
    B0 = relu_pack(D0); B1f = relu_pack(D1); B2f = relu_pack(D2); B3f = relu_pack(D3);
    // layer 4
    D0 = MFMA16(A4, B0, C4);  D1 = MFMA16(A4, B1f, C4);
    D2 = MFMA16(A4, B2f, C4); D3 = MFMA16(A4, B3f, C4);
    B0 = relu_pack(D0); B1f = relu_pack(D1); B2f = relu_pack(D2); B3f = relu_pack(D3);
    // layer 5 (M padded 3->16, no relu)
    D0 = MFMA16(A5, B0, C5);  D1 = MFMA16(A5, B1f, C5);
    D2 = MFMA16(A5, B2f, C5); D3 = MFMA16(A5, B3f, C5);

    // ---- store: D col=point (jj), row=output dim (4*kg+e) => lanes kg==0
    //      hold dims 0-2 of their group's point in regs 0-2 ----
    if (kg == 0) {
        const int gbase = blockIdx.x * BLK + wv * 64 + jj;
#define STOREG(Dv, g)                                                        \
        {                                                                    \
            int gp = gbase + (g) * 16;                                       \
            if (gp < n) {                                                    \
                out[3 * gp]     = (Dv)[0];                                   \
                out[3 * gp + 1] = (Dv)[1];                                   \
                out[3 * gp + 2] = (Dv)[2];                                   \
            }                                                                \
        }
        STOREG(D0, 0) STOREG(D1, 1) STOREG(D2, 2) STOREG(D3, 3)
#undef STOREG
    }
}

extern "C" void kernel_launch(void* const* d_in, const int* in_sizes, int n_in,
                              void* d_out, int out_size, void* d_ws, size_t ws_size,
                              hipStream_t stream) {
    const float* x  = (const float*)d_in[0];
    const float* fm = (const float*)d_in[1];
    const float* W1 = (const float*)d_in[2];
    const float* b1 = (const float*)d_in[3];
    const float* W2 = (const float*)d_in[4];
    const float* b2 = (const float*)d_in[5];
    const float* W3 = (const float*)d_in[6];
    const float* b3 = (const float*)d_in[7];
    const float* W4 = (const float*)d_in[8];
    const float* b4 = (const float*)d_in[9];
    const float* W5 = (const float*)d_in[10];
    const float* b5 = (const float*)d_in[11];
    float* out = (float*)d_out;

    const int n = in_sizes[0] / 3;  // 4,000,000 points
    const int grid = (n + BLK - 1) / BLK;

    const size_t need = (size_t)HWSZ * sizeof(f16x4);  // 2 MB f16 table
    if (ws_size >= need) {
        f16x4* fmT = (f16x4*)d_ws;
        fm_transpose_h<<<(HWSZ + 255) / 256, 256, 0, stream>>>(fm, fmT);
        mlp_fused<true><<<grid, BLK, 0, stream>>>(x, (const void*)fmT, W1, b1,
                                                  W2, b2, W3, b3, W4, b4, W5, b5,
                                                  out, n);
    } else {
        mlp_fused<false><<<grid, BLK, 0, stream>>>(x, (const void*)fm, W1, b1,
                                                   W2, b2, W3, b3, W4, b4, W5, b5,
                                                   out, n);
    }
}